// Round 3
// baseline (865.905 us; speedup 1.0000x reference)
//
#include <hip/hip_runtime.h>

#define DIN 128
#define DOUT 128
#define TILE_N 32

typedef float f4 __attribute__((ext_vector_type(4)));

// One edge per 128 threads; thread d handles feature d.
__global__ void scatter_kernel(const float* __restrict__ x,
                               const int* __restrict__ src,
                               const int* __restrict__ dst,
                               float* __restrict__ agg,
                               float* __restrict__ deg,
                               int nE) {
    long long idx = (long long)blockIdx.x * blockDim.x + threadIdx.x;
    int e = (int)(idx >> 7);
    int d = (int)(idx & 127);
    if (e >= nE) return;
    int s = src[e];
    int t = dst[e];
    float v = x[(long long)s * DIN + d];
    atomicAdd(&agg[(long long)t * DIN + d], v);
    if (d == 0) atomicAdd(&deg[t], 1.0f);
}

// out[n0..n0+31][:] (+)= (A/deg) @ W [+ bias] [relu]
__global__ __launch_bounds__(256, 2)
void gemm_kernel(const float* __restrict__ A,    // [N,128]
                 const float* __restrict__ deg,  // [N] or null (scale=1)
                 const float* __restrict__ W,    // [128,128]
                 const float* __restrict__ bias, // [128] or null
                 float* __restrict__ out,        // [N,128]
                 int nN, int accumulate, int applyRelu) {
    __shared__ float Ws[DIN * DOUT];        // 64 KB
    __shared__ float As[TILE_N * DIN];      // 16 KB
    __shared__ float sInv[TILE_N];

    const int tid = threadIdx.x;
    const int n0 = blockIdx.x * TILE_N;

    // Stage W: 16384 floats = 4096 float4, 16 per thread, coalesced.
    {
        const f4* Wv = (const f4*)W;
        f4* Wsv = (f4*)Ws;
        #pragma unroll
        for (int i = 0; i < 16; i++) Wsv[tid + i * 256] = Wv[tid + i * 256];
    }
    // Stage A tile: 4096 floats = 1024 float4, 4 per thread.
    {
        const f4* Av = (const f4*)(A + (long long)n0 * DIN);
        f4* Asv = (f4*)As;
        #pragma unroll
        for (int i = 0; i < 4; i++) {
            int li = tid + i * 256;
            int row = n0 + (li >> 5);
            if (row < nN) Asv[li] = Av[li];
        }
    }
    if (tid < TILE_N) {
        int row = n0 + tid;
        float s = 1.0f;
        if (deg != nullptr) {
            float dd = (row < nN) ? deg[row] : 1.0f;
            s = 1.0f / fmaxf(dd, 1.0f);
        }
        sInv[tid] = s;
    }
    __syncthreads();

    const int tx = tid & 31;   // dout group: columns tx*4..tx*4+3
    const int ty = tid >> 5;   // node group: rows ty*4..ty*4+3
    const int dbase = tx * 4;
    const int nbase = ty * 4;

    f4 acc[4];
    #pragma unroll
    for (int j = 0; j < 4; j++) acc[j] = (f4)(0.0f);

    for (int k0 = 0; k0 < DIN; k0 += 4) {
        f4 a[4], w[4];
        #pragma unroll
        for (int j = 0; j < 4; j++)
            a[j] = *(const f4*)&As[(nbase + j) * DIN + k0];
        #pragma unroll
        for (int kk = 0; kk < 4; kk++)
            w[kk] = *(const f4*)&Ws[(k0 + kk) * DOUT + dbase];
        #pragma unroll
        for (int j = 0; j < 4; j++) {
            #pragma unroll
            for (int kk = 0; kk < 4; kk++) {
                acc[j] += a[j][kk] * w[kk];
            }
        }
    }

    #pragma unroll
    for (int j = 0; j < 4; j++) {
        int row = n0 + nbase + j;
        if (row >= nN) continue;
        float s = sInv[nbase + j];
        f4 r = acc[j] * s;
        f4* op = (f4*)&out[(long long)row * DOUT + dbase];
        if (accumulate) r += *op;
        if (bias != nullptr) r += *(const f4*)&bias[dbase];
        if (applyRelu) {
            r.x = fmaxf(r.x, 0.0f);
            r.y = fmaxf(r.y, 0.0f);
            r.z = fmaxf(r.z, 0.0f);
            r.w = fmaxf(r.w, 0.0f);
        }
        *op = r;
    }
}

extern "C" void kernel_launch(void* const* d_in, const int* in_sizes, int n_in,
                              void* d_out, int out_size, void* d_ws, size_t ws_size,
                              hipStream_t stream) {
    const float* x  = (const float*)d_in[0];
    const float* W  = (const float*)d_in[1];
    const float* Wl = (const float*)d_in[2];
    const float* b  = (const float*)d_in[3];
    const int* src  = (const int*)d_in[4];
    const int* dst  = (const int*)d_in[5];
    float* out = (float*)d_out;

    const int N = in_sizes[0] / DIN;
    const int R = in_sizes[1] / (DIN * DOUT);
    const int E = in_sizes[4] / R;

    float* agg = (float*)d_ws;                  // [N,128]
    float* deg = agg + (size_t)N * DIN;         // [N]

    const int gemmGrid = (N + TILE_N - 1) / TILE_N;
    const int scatGrid = (int)(((long long)E * 128 + 255) / 256);

    // Pass 1: self-loop, overwrite out = x @ Wl + b.
    gemm_kernel<<<gemmGrid, 256, 0, stream>>>(x, nullptr, Wl, b, out, N, 0, 0);

    for (int r = 0; r < R; r++) {
        hipMemsetAsync(agg, 0, ((size_t)N * DIN + N) * sizeof(float), stream);
        scatter_kernel<<<scatGrid, 256, 0, stream>>>(
            x, src + (size_t)r * E, dst + (size_t)r * E, agg, deg, E);
        gemm_kernel<<<gemmGrid, 256, 0, stream>>>(
            agg, deg, W + (size_t)r * DIN * DOUT, nullptr, out, N,
            /*accumulate=*/1, /*applyRelu=*/(r == R - 1) ? 1 : 0);
    }
}

// Round 4
// 865.170 us; speedup vs baseline: 1.0008x; 1.0008x over previous
//
#include <hip/hip_runtime.h>

#define DIN 128
#define DOUT 128
#define TILE_N 32

typedef float f4 __attribute__((ext_vector_type(4)));

// One edge per 128 threads; thread d handles feature d.
__global__ void scatter_kernel(const float* __restrict__ x,
                               const int* __restrict__ src,
                               const int* __restrict__ dst,
                               float* __restrict__ agg,
                               float* __restrict__ deg,
                               int nE) {
    long long idx = (long long)blockIdx.x * blockDim.x + threadIdx.x;
    int e = (int)(idx >> 7);
    int d = (int)(idx & 127);
    if (e >= nE) return;
    int s = src[e];
    int t = dst[e];
    float v = x[(long long)s * DIN + d];
    atomicAdd(&agg[(long long)t * DIN + d], v);
    if (d == 0) atomicAdd(&deg[t], 1.0f);
}

// out[n0..n0+31][:] (+)= (A/deg) @ W [+ bias] [relu]
__global__ __launch_bounds__(256, 2)
void gemm_kernel(const float* __restrict__ A,    // [N,128]
                 const float* __restrict__ deg,  // [N] or null (scale=1)
                 const float* __restrict__ W,    // [128,128]
                 const float* __restrict__ bias, // [128] or null
                 float* __restrict__ out,        // [N,128]
                 int nN, int accumulate, int applyRelu) {
    __shared__ float Ws[DIN * DOUT];        // 64 KB
    __shared__ float As[TILE_N * DIN];      // 16 KB
    __shared__ float sInv[TILE_N];

    const int tid = threadIdx.x;
    const int n0 = blockIdx.x * TILE_N;

    // Stage W: 16384 floats = 4096 float4, 16 per thread, coalesced.
    {
        const f4* Wv = (const f4*)W;
        f4* Wsv = (f4*)Ws;
        #pragma unroll
        for (int i = 0; i < 16; i++) Wsv[tid + i * 256] = Wv[tid + i * 256];
    }
    // Stage A tile: 4096 floats = 1024 float4, 4 per thread.
    {
        const f4* Av = (const f4*)(A + (long long)n0 * DIN);
        f4* Asv = (f4*)As;
        #pragma unroll
        for (int i = 0; i < 4; i++) {
            int li = tid + i * 256;
            int row = n0 + (li >> 5);
            if (row < nN) Asv[li] = Av[li];
        }
    }
    if (tid < TILE_N) {
        int row = n0 + tid;
        float s = 1.0f;
        if (deg != nullptr) {
            float dd = (row < nN) ? deg[row] : 1.0f;
            s = 1.0f / fmaxf(dd, 1.0f);
        }
        sInv[tid] = s;
    }
    __syncthreads();

    const int tx = tid & 31;   // dout group: columns tx*4..tx*4+3
    const int ty = tid >> 5;   // node group: rows ty*4..ty*4+3
    const int dbase = tx * 4;
    const int nbase = ty * 4;

    f4 acc[4];
    #pragma unroll
    for (int j = 0; j < 4; j++) acc[j] = (f4)(0.0f);

    for (int k0 = 0; k0 < DIN; k0 += 4) {
        f4 a[4], w[4];
        #pragma unroll
        for (int j = 0; j < 4; j++)
            a[j] = *(const f4*)&As[(nbase + j) * DIN + k0];
        #pragma unroll
        for (int kk = 0; kk < 4; kk++)
            w[kk] = *(const f4*)&Ws[(k0 + kk) * DOUT + dbase];
        #pragma unroll
        for (int j = 0; j < 4; j++) {
            #pragma unroll
            for (int kk = 0; kk < 4; kk++) {
                acc[j] += a[j][kk] * w[kk];
            }
        }
    }

    #pragma unroll
    for (int j = 0; j < 4; j++) {
        int row = n0 + nbase + j;
        if (row >= nN) continue;
        float s = sInv[nbase + j];
        f4 r = acc[j] * s;
        f4* op = (f4*)&out[(long long)row * DOUT + dbase];
        if (accumulate) r += *op;
        if (bias != nullptr) r += *(const f4*)&bias[dbase];
        if (applyRelu) {
            r.x = fmaxf(r.x, 0.0f);
            r.y = fmaxf(r.y, 0.0f);
            r.z = fmaxf(r.z, 0.0f);
            r.w = fmaxf(r.w, 0.0f);
        }
        *op = r;
    }
}

extern "C" void kernel_launch(void* const* d_in, const int* in_sizes, int n_in,
                              void* d_out, int out_size, void* d_ws, size_t ws_size,
                              hipStream_t stream) {
    const float* x  = (const float*)d_in[0];
    const float* W  = (const float*)d_in[1];
    const float* Wl = (const float*)d_in[2];
    const float* b  = (const float*)d_in[3];
    const int* src  = (const int*)d_in[4];
    const int* dst  = (const int*)d_in[5];
    float* out = (float*)d_out;

    const int N = in_sizes[0] / DIN;
    const int R = in_sizes[1] / (DIN * DOUT);
    const int E = in_sizes[4] / R;

    float* agg = (float*)d_ws;                  // [N,128]
    float* deg = agg + (size_t)N * DIN;         // [N]

    const int gemmGrid = (N + TILE_N - 1) / TILE_N;
    const int scatGrid = (int)(((long long)E * 128 + 255) / 256);

    // Pass 1: self-loop, overwrite out = x @ Wl + b.
    gemm_kernel<<<gemmGrid, 256, 0, stream>>>(x, nullptr, Wl, b, out, N, 0, 0);

    for (int r = 0; r < R; r++) {
        hipMemsetAsync(agg, 0, ((size_t)N * DIN + N) * sizeof(float), stream);
        scatter_kernel<<<scatGrid, 256, 0, stream>>>(
            x, src + (size_t)r * E, dst + (size_t)r * E, agg, deg, E);
        gemm_kernel<<<gemmGrid, 256, 0, stream>>>(
            agg, deg, W + (size_t)r * DIN * DOUT, nullptr, out, N,
            /*accumulate=*/1, /*applyRelu=*/(r == R - 1) ? 1 : 0);
    }
}